// Round 8
// baseline (176.188 us; speedup 1.0000x reference)
//
#include <hip/hip_runtime.h>
#include <hip/hip_fp16.h>

#define NEG 0.2f
#define BNEPS 1e-5f
#define NPART 256

// ---------------- GEMM1: h1 = x @ W1^T  [N,128] (fp16 pairs) + s_src1/s_dst1 [N,4] ----------------
__global__ __launch_bounds__(256) void gemm1_kernel(
    const float* __restrict__ x, const float* __restrict__ W1,
    const float* __restrict__ asrc, const float* __restrict__ adst,
    __half2* __restrict__ h1h, float* __restrict__ ssrc1, float* __restrict__ sdst1, int n)
{
    __shared__ float At[32 * 68];    // [k][row]
    __shared__ float Bt[32 * 132];   // [k][col]
    int tid = threadIdx.x;
    int tx = tid & 15, ty = tid >> 4;
    int rbase = blockIdx.x * 64;

    int arow = tid >> 2, aq = tid & 3;
    int bc = tid >> 1, bq = tid & 1;
    int grow = rbase + arow;
    bool aval = grow < n;
    const float* xrow = x + (size_t)grow * 128;
    const float* wrow = W1 + (size_t)bc * 128;

    float acc_lo[4][4] = {{0.f}};
    float acc_hi[4][4] = {{0.f}};

    for (int kb = 0; kb < 128; kb += 32) {
        float4 av0, av1;
        if (aval) {
            av0 = *(const float4*)(xrow + kb + aq * 8);
            av1 = *(const float4*)(xrow + kb + aq * 8 + 4);
        } else {
            av0 = make_float4(0.f, 0.f, 0.f, 0.f); av1 = av0;
        }
        float4 bv0 = *(const float4*)(wrow + kb + bq * 16);
        float4 bv1 = *(const float4*)(wrow + kb + bq * 16 + 4);
        float4 bv2 = *(const float4*)(wrow + kb + bq * 16 + 8);
        float4 bv3 = *(const float4*)(wrow + kb + bq * 16 + 12);
        __syncthreads();
        {
            const float* a0 = (const float*)&av0;
            const float* a1 = (const float*)&av1;
#pragma unroll
            for (int j = 0; j < 4; ++j) At[(aq * 8 + j) * 68 + arow] = a0[j];
#pragma unroll
            for (int j = 0; j < 4; ++j) At[(aq * 8 + 4 + j) * 68 + arow] = a1[j];
            const float* bp0 = (const float*)&bv0;
            const float* bp1 = (const float*)&bv1;
            const float* bp2 = (const float*)&bv2;
            const float* bp3 = (const float*)&bv3;
#pragma unroll
            for (int j = 0; j < 4; ++j) Bt[(bq * 16 + j) * 132 + bc] = bp0[j];
#pragma unroll
            for (int j = 0; j < 4; ++j) Bt[(bq * 16 + 4 + j) * 132 + bc] = bp1[j];
#pragma unroll
            for (int j = 0; j < 4; ++j) Bt[(bq * 16 + 8 + j) * 132 + bc] = bp2[j];
#pragma unroll
            for (int j = 0; j < 4; ++j) Bt[(bq * 16 + 12 + j) * 132 + bc] = bp3[j];
        }
        __syncthreads();
#pragma unroll
        for (int k = 0; k < 32; ++k) {
            float4 af = *(const float4*)&At[k * 68 + ty * 4];
            float4 bl = *(const float4*)&Bt[k * 132 + tx * 4];
            float4 bh = *(const float4*)&Bt[k * 132 + 64 + tx * 4];
            const float* ap = (const float*)&af;
            const float* blp = (const float*)&bl;
            const float* bhp = (const float*)&bh;
#pragma unroll
            for (int r = 0; r < 4; ++r) {
#pragma unroll
                for (int j = 0; j < 4; ++j) {
                    acc_lo[r][j] += ap[r] * blp[j];
                    acc_hi[r][j] += ap[r] * bhp[j];
                }
            }
        }
    }

    float4 as_lo = *(const float4*)(asrc + 4 * tx);
    float4 as_hi = *(const float4*)(asrc + 64 + 4 * tx);
    float4 ad_lo = *(const float4*)(adst + 4 * tx);
    float4 ad_hi = *(const float4*)(adst + 64 + 4 * tx);
    const float* aslp = (const float*)&as_lo;
    const float* ashp = (const float*)&as_hi;
    const float* adlp = (const float*)&ad_lo;
    const float* adhp = (const float*)&ad_hi;

#pragma unroll
    for (int r = 0; r < 4; ++r) {
        int row = rbase + 4 * ty + r;
        if (row >= n) continue;
        __half2* hp = h1h + (size_t)row * 64;
        hp[2 * tx]     = __floats2half2_rn(acc_lo[r][0], acc_lo[r][1]);
        hp[2 * tx + 1] = __floats2half2_rn(acc_lo[r][2], acc_lo[r][3]);
        hp[32 + 2 * tx]     = __floats2half2_rn(acc_hi[r][0], acc_hi[r][1]);
        hp[32 + 2 * tx + 1] = __floats2half2_rn(acc_hi[r][2], acc_hi[r][3]);
        float sls = 0.f, sld = 0.f, shs = 0.f, shd = 0.f;
#pragma unroll
        for (int j = 0; j < 4; ++j) {
            sls += acc_lo[r][j] * aslp[j];
            sld += acc_lo[r][j] * adlp[j];
            shs += acc_hi[r][j] * ashp[j];
            shd += acc_hi[r][j] * adhp[j];
        }
#pragma unroll
        for (int m = 1; m <= 4; m <<= 1) {
            sls += __shfl_xor(sls, m, 64);
            sld += __shfl_xor(sld, m, 64);
            shs += __shfl_xor(shs, m, 64);
            shd += __shfl_xor(shd, m, 64);
        }
        if ((tx & 7) == 0) {
            int hl = tx >> 3;
            ssrc1[row * 4 + hl] = sls;
            sdst1[row * 4 + hl] = sld;
            ssrc1[row * 4 + 2 + hl] = shs;
            sdst1[row * 4 + 2 + hl] = shd;
        }
    }
}

// ---------------- CSR pass 1: partition edges into 256 dst-range buckets ----------------
__global__ __launch_bounds__(256) void part_kernel(
    const int* __restrict__ srcp, const int* __restrict__ dstp, int E, int Etot, int chunk,
    int2* __restrict__ pairs, int pcap, int* __restrict__ pcur)
{
    __shared__ int lcnt[NPART], lbase[NPART];
    const int PER = 8;
    int t0 = blockIdx.x * 256 * PER;
    int tid = threadIdx.x;
    lcnt[tid] = 0;
    __syncthreads();
    int myd[PER], mys[PER], myp[PER];
#pragma unroll
    for (int j = 0; j < PER; ++j) {
        int i = t0 + j * 256 + tid;
        if (i < Etot) {
            int s, d;
            if (i < E) { s = srcp[i]; d = dstp[i]; } else { s = i - E; d = i - E; }
            myd[j] = d; mys[j] = s; myp[j] = d / chunk;
            atomicAdd(&lcnt[myp[j]], 1);
        } else myp[j] = -1;
    }
    __syncthreads();
    lbase[tid] = atomicAdd(&pcur[tid], lcnt[tid]);
    lcnt[tid] = 0;
    __syncthreads();
#pragma unroll
    for (int j = 0; j < PER; ++j) {
        if (myp[j] >= 0) {
            int r = atomicAdd(&lcnt[myp[j]], 1);
            int pos = lbase[myp[j]] + r;
            if (pos < pcap) pairs[(size_t)myp[j] * pcap + pos] = make_int2(myd[j], mys[j]);
        }
    }
}

// ---------------- CSR pass 2 + layer-1 edge weights ----------------
// One block per partition: deg count, scan, scatter col/dstarr, and w1[pos] = exp(leaky(ssrc1+sdst1)).
__global__ __launch_bounds__(256) void csr_kernel(
    const int2* __restrict__ pairs, int pcap, const int* __restrict__ pcnt,
    const float* __restrict__ ssrc1, const float* __restrict__ sdst1,
    int* __restrict__ rowptr, int* __restrict__ col, int* __restrict__ dstarr,
    float4* __restrict__ w1, int N, int chunk, int Etot)
{
    __shared__ int ldeg[NPART];
    __shared__ int wtmp[4];
    __shared__ int sh_pbase;
    __shared__ float sdl[NPART * 4];   // sdst1 slice (chunk<=256)
    int p = blockIdx.x;
    int lo = p * chunk;
    int hi = min(lo + chunk, N);
    int len = max(hi - lo, 0);
    int tid = threadIdx.x;
    int lane = tid & 63, wv = tid >> 6;

    {
        int v = pcnt[tid];
        int inc = v;
#pragma unroll
        for (int m = 1; m < 64; m <<= 1) {
            int t = __shfl_up(inc, m, 64);
            if (lane >= m) inc += t;
        }
        if (lane == 63) wtmp[wv] = inc;
        __syncthreads();
        int woff = 0;
        for (int w = 0; w < wv; ++w) woff += wtmp[w];
        if (tid == p) sh_pbase = inc - v + woff;
        ldeg[tid] = 0;
    }
    for (int i = tid; i < len * 4; i += 256) sdl[i] = sdst1[lo * 4 + i];
    __syncthreads();

    int cnt = min(pcnt[p], pcap);
    const int2* pp = pairs + (size_t)p * pcap;
    for (int i = tid; i < cnt; i += 256) {
        atomicAdd(&ldeg[pp[i].x - lo], 1);
    }
    __syncthreads();

    int v = (tid < len) ? ldeg[tid] : 0;
    int inc = v;
#pragma unroll
    for (int m = 1; m < 64; m <<= 1) {
        int t = __shfl_up(inc, m, 64);
        if (lane >= m) inc += t;
    }
    if (lane == 63) wtmp[wv] = inc;
    __syncthreads();
    int woff = 0;
    for (int w = 0; w < wv; ++w) woff += wtmp[w];
    int excl = inc - v + woff;
    int base = sh_pbase;
    __syncthreads();
    if (tid < len) {
        rowptr[lo + tid] = base + excl;
        ldeg[tid] = base + excl;
    }
    if (p == NPART - 1 && tid == 0) rowptr[N] = Etot;
    __syncthreads();

    for (int i = tid; i < cnt; i += 256) {
        int2 e = pp[i];
        int pos = atomicAdd(&ldeg[e.x - lo], 1);
        col[pos] = e.y;
        dstarr[pos] = e.x;
        float4 sv = *(const float4*)(ssrc1 + (size_t)e.y * 4);
        const float* dv = &sdl[(e.x - lo) * 4];
        float4 wv4;
        float e0 = sv.x + dv[0]; e0 = (e0 > 0.f) ? e0 : NEG * e0; wv4.x = __expf(e0);
        float e1 = sv.y + dv[1]; e1 = (e1 > 0.f) ? e1 : NEG * e1; wv4.y = __expf(e1);
        float e2 = sv.z + dv[2]; e2 = (e2 > 0.f) ? e2 : NEG * e2; wv4.z = __expf(e2);
        float e3 = sv.w + dv[3]; e3 = (e3 > 0.f) ? e3 : NEG * e3; wv4.w = __expf(e3);
        w1[pos] = wv4;
    }
}

// ---------------- layer-2 edge weights (edge-major, streaming) ----------------
__global__ __launch_bounds__(256) void w2_kernel(
    const int* __restrict__ col, const int* __restrict__ dstarr,
    const float* __restrict__ ssrc2, const float* __restrict__ sdst2,
    float* __restrict__ w2, int Etot)
{
    int i = blockIdx.x * 256 + threadIdx.x;
    if (i >= Etot) return;
    float e = ssrc2[col[i]] + sdst2[dstarr[i]];
    e = (e > 0.f) ? e : NEG * e;
    w2[i] = __expf(e);
}

// ---------------- GAT layer-1: pure gather+FMA aggregate + bias + BN1 + ELU ----------------
// Wave = 4 groups x 16 lanes; group g takes edges start+g, +4,... Lane (g,q) owns channels 8q..8q+7.
__global__ __launch_bounds__(256) void agg1_kernel(
    const __half2* __restrict__ h1h, const float* __restrict__ w1f,
    const int* __restrict__ rowptr, const int* __restrict__ col,
    const float* __restrict__ b1, const float* __restrict__ g1, const float* __restrict__ be1,
    const float* __restrict__ mu1, const float* __restrict__ var1,
    float* __restrict__ hbn1, int n)
{
    int node = blockIdx.x * 4 + (threadIdx.x >> 6);
    int lane = threadIdx.x & 63;
    if (node >= n) return;
    int start = rowptr[node], end = rowptr[node + 1];
    int g = lane >> 4;          // edge group
    int q = lane & 15;          // channel quad
    int hd = q >> 2;            // head of my 8 channels

    float acc[8] = {0.f, 0.f, 0.f, 0.f, 0.f, 0.f, 0.f, 0.f};
    float dn = 0.f;
#pragma unroll 2
    for (int j = start + g; j < end; j += 4) {
        int s = col[j];
        float w = w1f[j * 4 + hd];
        dn += w;
        float4 hv = *(const float4*)((const char*)(h1h + (size_t)s * 64) + 16 * q);
        const __half2* hp = (const __half2*)&hv;
#pragma unroll
        for (int t = 0; t < 4; ++t) {
            float2 f = __half22float2(hp[t]);
            acc[2 * t]     += w * f.x;
            acc[2 * t + 1] += w * f.y;
        }
    }
#pragma unroll
    for (int m = 16; m <= 32; m <<= 1) {
        dn += __shfl_xor(dn, m, 64);
#pragma unroll
        for (int t = 0; t < 8; ++t) acc[t] += __shfl_xor(acc[t], m, 64);
    }
    if (lane < 16) {
        float iv = 1.f / dn;
        int c = 8 * q;
        float4 b0 = *(const float4*)(b1 + c),   b4 = *(const float4*)(b1 + c + 4);
        float4 g0 = *(const float4*)(g1 + c),   g4 = *(const float4*)(g1 + c + 4);
        float4 e0 = *(const float4*)(be1 + c),  e4 = *(const float4*)(be1 + c + 4);
        float4 m0 = *(const float4*)(mu1 + c),  m4 = *(const float4*)(mu1 + c + 4);
        float4 v0 = *(const float4*)(var1 + c), v4 = *(const float4*)(var1 + c + 4);
        const float* bp = (const float*)&b0;  const float* bp4 = (const float*)&b4;
        const float* gp = (const float*)&g0;  const float* gp4 = (const float*)&g4;
        const float* ep = (const float*)&e0;  const float* ep4 = (const float*)&e4;
        const float* mp = (const float*)&m0;  const float* mp4 = (const float*)&m4;
        const float* vp = (const float*)&v0;  const float* vp4 = (const float*)&v4;
        float out[8];
#pragma unroll
        for (int t = 0; t < 4; ++t) {
            float u = acc[t] * iv + bp[t];
            u = (u - mp[t]) * (gp[t] * rsqrtf(vp[t] + BNEPS)) + ep[t];
            out[t] = (u > 0.f) ? u : (__expf(u) - 1.f);
        }
#pragma unroll
        for (int t = 0; t < 4; ++t) {
            float u = acc[4 + t] * iv + bp4[t];
            u = (u - mp4[t]) * (gp4[t] * rsqrtf(vp4[t] + BNEPS)) + ep4[t];
            out[4 + t] = (u > 0.f) ? u : (__expf(u) - 1.f);
        }
        float* op = hbn1 + (size_t)node * 128 + c;
        *(float4*)op       = make_float4(out[0], out[1], out[2], out[3]);
        *(float4*)(op + 4) = make_float4(out[4], out[5], out[6], out[7]);
    }
}

// ---------------- GEMM2: h2 = hbn1 @ W2^T  [N,32] (fp16 pairs) + s_src2/s_dst2 [N] ----------------
__global__ __launch_bounds__(256) void gemm2_kernel(
    const float* __restrict__ hbn1, const float* __restrict__ W2,
    const float* __restrict__ asrc2, const float* __restrict__ adst2,
    __half2* __restrict__ h2h, float* __restrict__ ssrc2, float* __restrict__ sdst2, int n)
{
    __shared__ float At[32 * 68];
    __shared__ float Bt[32 * 36];
    int tid = threadIdx.x;
    int tx = tid & 15, ty = tid >> 4;
    int rbase = blockIdx.x * 64;

    int arow = tid >> 2, aq = tid & 3;
    int bc = tid >> 3, bq = tid & 7;
    int grow = rbase + arow;
    bool aval = grow < n;
    const float* xrow = hbn1 + (size_t)grow * 128;
    const float* wrow = W2 + (size_t)bc * 128;

    float acc[4][2] = {{0.f}};

    for (int kb = 0; kb < 128; kb += 32) {
        float4 av0, av1;
        if (aval) {
            av0 = *(const float4*)(xrow + kb + aq * 8);
            av1 = *(const float4*)(xrow + kb + aq * 8 + 4);
        } else {
            av0 = make_float4(0.f, 0.f, 0.f, 0.f); av1 = av0;
        }
        float4 bv = *(const float4*)(wrow + kb + bq * 4);
        __syncthreads();
        {
            const float* a0 = (const float*)&av0;
            const float* a1 = (const float*)&av1;
#pragma unroll
            for (int j = 0; j < 4; ++j) At[(aq * 8 + j) * 68 + arow] = a0[j];
#pragma unroll
            for (int j = 0; j < 4; ++j) At[(aq * 8 + 4 + j) * 68 + arow] = a1[j];
            const float* bp = (const float*)&bv;
#pragma unroll
            for (int j = 0; j < 4; ++j) Bt[(bq * 4 + j) * 36 + bc] = bp[j];
        }
        __syncthreads();
#pragma unroll
        for (int k = 0; k < 32; ++k) {
            float4 af = *(const float4*)&At[k * 68 + ty * 4];
            float2 bf = *(const float2*)&Bt[k * 36 + 2 * tx];
            const float* ap = (const float*)&af;
#pragma unroll
            for (int r = 0; r < 4; ++r) {
                acc[r][0] += ap[r] * bf.x;
                acc[r][1] += ap[r] * bf.y;
            }
        }
    }

    float as0 = asrc2[2 * tx], as1 = asrc2[2 * tx + 1];
    float ad0 = adst2[2 * tx], ad1 = adst2[2 * tx + 1];
#pragma unroll
    for (int r = 0; r < 4; ++r) {
        int row = rbase + 4 * ty + r;
        if (row >= n) continue;
        h2h[(size_t)row * 16 + tx] = __floats2half2_rn(acc[r][0], acc[r][1]);
        float ts = acc[r][0] * as0 + acc[r][1] * as1;
        float td = acc[r][0] * ad0 + acc[r][1] * ad1;
#pragma unroll
        for (int m = 1; m <= 8; m <<= 1) {
            ts += __shfl_xor(ts, m, 64);
            td += __shfl_xor(td, m, 64);
        }
        if (tx == 0) { ssrc2[row] = ts; sdst2[row] = td; }
    }
}

// ---------------- GAT layer-2: gather+FMA aggregate + BN2 + ELU + classifier ----------------
__global__ __launch_bounds__(256) void agg2_kernel(
    const __half2* __restrict__ h2h, const float* __restrict__ w2,
    const int* __restrict__ rowptr, const int* __restrict__ col,
    const float* __restrict__ b2, const float* __restrict__ g2, const float* __restrict__ be2,
    const float* __restrict__ mu2, const float* __restrict__ var2,
    const float* __restrict__ Wc, const float* __restrict__ bc,
    float* __restrict__ out, int n)
{
    int node = blockIdx.x * 4 + (threadIdx.x >> 6);
    int lane = threadIdx.x & 63;
    if (node >= n) return;
    int start = rowptr[node], end = rowptr[node + 1];
    int cp = lane & 15, sub = lane >> 4;
    float accx = 0.f, accy = 0.f, dn = 0.f;
    for (int j = start + sub; j < end; j += 4) {
        int s = col[j];
        float w = w2[j];
        dn += w;
        float2 hf = __half22float2(h2h[(size_t)s * 16 + cp]);
        accx += w * hf.x;
        accy += w * hf.y;
    }
    accx += __shfl_xor(accx, 16, 64); accx += __shfl_xor(accx, 32, 64);
    accy += __shfl_xor(accy, 16, 64); accy += __shfl_xor(accy, 32, 64);
    dn   += __shfl_xor(dn,   16, 64); dn   += __shfl_xor(dn,   32, 64);
    float iv = 1.f / dn;
    int c0 = 2 * cp, c1 = c0 + 1;
    float v0 = accx * iv + b2[c0];
    v0 = (v0 - mu2[c0]) * (g2[c0] * rsqrtf(var2[c0] + BNEPS)) + be2[c0];
    v0 = (v0 > 0.f) ? v0 : (__expf(v0) - 1.f);
    float v1 = accy * iv + b2[c1];
    v1 = (v1 - mu2[c1]) * (g2[c1] * rsqrtf(var2[c1] + BNEPS)) + be2[c1];
    v1 = (v1 > 0.f) ? v1 : (__expf(v1) - 1.f);
#pragma unroll
    for (int rr = 0; rr < 3; ++rr) {
        int o = sub + rr * 4;
        float t = 0.f;
        if (o < 10) t = v0 * Wc[o * 32 + c0] + v1 * Wc[o * 32 + c1];
#pragma unroll
        for (int m = 8; m >= 1; m >>= 1) t += __shfl_xor(t, m, 64);
        if (cp == 0 && o < 10) out[(size_t)node * 10 + o] = t + bc[o];
    }
}

extern "C" void kernel_launch(void* const* d_in, const int* in_sizes, int n_in,
                              void* d_out, int out_size, void* d_ws, size_t ws_size,
                              hipStream_t stream)
{
    const float* x     = (const float*)d_in[0];
    const int*   ei    = (const int*)d_in[1];
    const float* W1    = (const float*)d_in[2];
    const float* asrc1 = (const float*)d_in[3];
    const float* adst1 = (const float*)d_in[4];
    const float* b1    = (const float*)d_in[5];
    const float* g1    = (const float*)d_in[6];
    const float* be1   = (const float*)d_in[7];
    const float* mu1   = (const float*)d_in[8];
    const float* var1  = (const float*)d_in[9];
    const float* W2    = (const float*)d_in[10];
    const float* asrc2 = (const float*)d_in[11];
    const float* adst2 = (const float*)d_in[12];
    const float* b2    = (const float*)d_in[13];
    const float* g2    = (const float*)d_in[14];
    const float* be2   = (const float*)d_in[15];
    const float* mu2   = (const float*)d_in[16];
    const float* var2  = (const float*)d_in[17];
    const float* Wc    = (const float*)d_in[18];
    const float* bc    = (const float*)d_in[19];

    int N_ = in_sizes[0] / 128;
    int E_ = in_sizes[1] / 2;
    int Etot = E_ + N_;
    const int* srcp = ei;
    const int* dstp = ei + E_;
    int chunk = (N_ + NPART - 1) / NPART;
    int pcap = Etot / NPART + 1024;

    char* ws = (char*)d_ws;
    size_t off = 0;
    auto alloc = [&](size_t bytes) -> char* {
        char* p = ws + off;
        off += (bytes + 255) & ~(size_t)255;
        return p;
    };
    __half2* h1h   = (__half2*)alloc((size_t)N_ * 64 * 4);
    float*   hbn1  = (float*)alloc((size_t)N_ * 128 * 4);
    __half2* h2h   = (__half2*)alloc((size_t)N_ * 16 * 4);
    float*   ssrc1 = (float*)alloc((size_t)N_ * 4 * 4);
    float*   sdst1 = (float*)alloc((size_t)N_ * 4 * 4);
    float*   ssrc2 = (float*)alloc((size_t)N_ * 4);
    float*   sdst2 = (float*)alloc((size_t)N_ * 4);
    int*     rowptr= (int*)alloc((size_t)(N_ + 1) * 4);
    int*     col   = (int*)alloc((size_t)Etot * 4);
    int*     dstarr= (int*)alloc((size_t)Etot * 4);
    float4*  w1    = (float4*)alloc((size_t)Etot * 16);
    float*   w2    = (float*)alloc((size_t)Etot * 4);
    int2*    pairs = (int2*)alloc((size_t)NPART * pcap * 8);
    int*     pcur  = (int*)alloc((size_t)NPART * 4);

    hipMemsetAsync(pcur, 0, NPART * 4, stream);
    gemm1_kernel<<<(N_ + 63) / 64, 256, 0, stream>>>(x, W1, asrc1, adst1, h1h, ssrc1, sdst1, N_);
    int per_block = 256 * 8;
    part_kernel<<<(Etot + per_block - 1) / per_block, 256, 0, stream>>>(
        srcp, dstp, E_, Etot, chunk, pairs, pcap, pcur);
    csr_kernel<<<NPART, 256, 0, stream>>>(pairs, pcap, pcur, ssrc1, sdst1,
                                          rowptr, col, dstarr, w1, N_, chunk, Etot);
    agg1_kernel<<<(N_ + 3) / 4, 256, 0, stream>>>(h1h, (const float*)w1, rowptr, col,
                                                  b1, g1, be1, mu1, var1, hbn1, N_);
    gemm2_kernel<<<(N_ + 63) / 64, 256, 0, stream>>>(hbn1, W2, asrc2, adst2, h2h, ssrc2, sdst2, N_);
    w2_kernel<<<(Etot + 255) / 256, 256, 0, stream>>>(col, dstarr, ssrc2, sdst2, w2, Etot);
    agg2_kernel<<<(N_ + 3) / 4, 256, 0, stream>>>(h2h, w2, rowptr, col,
                                                  b2, g2, be2, mu2, var2, Wc, bc, (float*)d_out, N_);
}

// Round 9
// 170.154 us; speedup vs baseline: 1.0355x; 1.0355x over previous
//
#include <hip/hip_runtime.h>
#include <hip/hip_fp16.h>

#define NEG 0.2f
#define BNEPS 1e-5f
#define NPART 256

// ---------------- GEMM1: h1 = x @ W1^T  [N,128] (fp16 pairs) + s_src1/s_dst1 [N,4] ----------------
__global__ __launch_bounds__(256) void gemm1_kernel(
    const float* __restrict__ x, const float* __restrict__ W1,
    const float* __restrict__ asrc, const float* __restrict__ adst,
    __half2* __restrict__ h1h, float* __restrict__ ssrc1, float* __restrict__ sdst1, int n)
{
    __shared__ float At[32 * 68];    // [k][row]
    __shared__ float Bt[32 * 132];   // [k][col]
    int tid = threadIdx.x;
    int tx = tid & 15, ty = tid >> 4;
    int rbase = blockIdx.x * 64;

    int arow = tid >> 2, aq = tid & 3;
    int bc = tid >> 1, bq = tid & 1;
    int grow = rbase + arow;
    bool aval = grow < n;
    const float* xrow = x + (size_t)grow * 128;
    const float* wrow = W1 + (size_t)bc * 128;

    float acc_lo[4][4] = {{0.f}};
    float acc_hi[4][4] = {{0.f}};

    for (int kb = 0; kb < 128; kb += 32) {
        float4 av0, av1;
        if (aval) {
            av0 = *(const float4*)(xrow + kb + aq * 8);
            av1 = *(const float4*)(xrow + kb + aq * 8 + 4);
        } else {
            av0 = make_float4(0.f, 0.f, 0.f, 0.f); av1 = av0;
        }
        float4 bv0 = *(const float4*)(wrow + kb + bq * 16);
        float4 bv1 = *(const float4*)(wrow + kb + bq * 16 + 4);
        float4 bv2 = *(const float4*)(wrow + kb + bq * 16 + 8);
        float4 bv3 = *(const float4*)(wrow + kb + bq * 16 + 12);
        __syncthreads();
        {
            const float* a0 = (const float*)&av0;
            const float* a1 = (const float*)&av1;
#pragma unroll
            for (int j = 0; j < 4; ++j) At[(aq * 8 + j) * 68 + arow] = a0[j];
#pragma unroll
            for (int j = 0; j < 4; ++j) At[(aq * 8 + 4 + j) * 68 + arow] = a1[j];
            const float* bp0 = (const float*)&bv0;
            const float* bp1 = (const float*)&bv1;
            const float* bp2 = (const float*)&bv2;
            const float* bp3 = (const float*)&bv3;
#pragma unroll
            for (int j = 0; j < 4; ++j) Bt[(bq * 16 + j) * 132 + bc] = bp0[j];
#pragma unroll
            for (int j = 0; j < 4; ++j) Bt[(bq * 16 + 4 + j) * 132 + bc] = bp1[j];
#pragma unroll
            for (int j = 0; j < 4; ++j) Bt[(bq * 16 + 8 + j) * 132 + bc] = bp2[j];
#pragma unroll
            for (int j = 0; j < 4; ++j) Bt[(bq * 16 + 12 + j) * 132 + bc] = bp3[j];
        }
        __syncthreads();
#pragma unroll
        for (int k = 0; k < 32; ++k) {
            float4 af = *(const float4*)&At[k * 68 + ty * 4];
            float4 bl = *(const float4*)&Bt[k * 132 + tx * 4];
            float4 bh = *(const float4*)&Bt[k * 132 + 64 + tx * 4];
            const float* ap = (const float*)&af;
            const float* blp = (const float*)&bl;
            const float* bhp = (const float*)&bh;
#pragma unroll
            for (int r = 0; r < 4; ++r) {
#pragma unroll
                for (int j = 0; j < 4; ++j) {
                    acc_lo[r][j] += ap[r] * blp[j];
                    acc_hi[r][j] += ap[r] * bhp[j];
                }
            }
        }
    }

    float4 as_lo = *(const float4*)(asrc + 4 * tx);
    float4 as_hi = *(const float4*)(asrc + 64 + 4 * tx);
    float4 ad_lo = *(const float4*)(adst + 4 * tx);
    float4 ad_hi = *(const float4*)(adst + 64 + 4 * tx);
    const float* aslp = (const float*)&as_lo;
    const float* ashp = (const float*)&as_hi;
    const float* adlp = (const float*)&ad_lo;
    const float* adhp = (const float*)&ad_hi;

#pragma unroll
    for (int r = 0; r < 4; ++r) {
        int row = rbase + 4 * ty + r;
        if (row >= n) continue;
        __half2* hp = h1h + (size_t)row * 64;
        hp[2 * tx]     = __floats2half2_rn(acc_lo[r][0], acc_lo[r][1]);
        hp[2 * tx + 1] = __floats2half2_rn(acc_lo[r][2], acc_lo[r][3]);
        hp[32 + 2 * tx]     = __floats2half2_rn(acc_hi[r][0], acc_hi[r][1]);
        hp[32 + 2 * tx + 1] = __floats2half2_rn(acc_hi[r][2], acc_hi[r][3]);
        float sls = 0.f, sld = 0.f, shs = 0.f, shd = 0.f;
#pragma unroll
        for (int j = 0; j < 4; ++j) {
            sls += acc_lo[r][j] * aslp[j];
            sld += acc_lo[r][j] * adlp[j];
            shs += acc_hi[r][j] * ashp[j];
            shd += acc_hi[r][j] * adhp[j];
        }
#pragma unroll
        for (int m = 1; m <= 4; m <<= 1) {
            sls += __shfl_xor(sls, m, 64);
            sld += __shfl_xor(sld, m, 64);
            shs += __shfl_xor(shs, m, 64);
            shd += __shfl_xor(shd, m, 64);
        }
        if ((tx & 7) == 0) {
            int hl = tx >> 3;
            ssrc1[row * 4 + hl] = sls;
            sdst1[row * 4 + hl] = sld;
            ssrc1[row * 4 + 2 + hl] = shs;
            sdst1[row * 4 + 2 + hl] = shd;
        }
    }
}

// ---------------- CSR pass 1: partition edges into 256 dst-range buckets ----------------
__global__ __launch_bounds__(256) void part_kernel(
    const int* __restrict__ srcp, const int* __restrict__ dstp, int E, int Etot, int chunk,
    int2* __restrict__ pairs, int pcap, int* __restrict__ pcur)
{
    __shared__ int lcnt[NPART], lbase[NPART];
    const int PER = 8;
    int t0 = blockIdx.x * 256 * PER;
    int tid = threadIdx.x;
    lcnt[tid] = 0;
    __syncthreads();
    int myd[PER], mys[PER], myp[PER];
#pragma unroll
    for (int j = 0; j < PER; ++j) {
        int i = t0 + j * 256 + tid;
        if (i < Etot) {
            int s, d;
            if (i < E) { s = srcp[i]; d = dstp[i]; } else { s = i - E; d = i - E; }
            myd[j] = d; mys[j] = s; myp[j] = d / chunk;
            atomicAdd(&lcnt[myp[j]], 1);
        } else myp[j] = -1;
    }
    __syncthreads();
    lbase[tid] = atomicAdd(&pcur[tid], lcnt[tid]);
    lcnt[tid] = 0;
    __syncthreads();
#pragma unroll
    for (int j = 0; j < PER; ++j) {
        if (myp[j] >= 0) {
            int r = atomicAdd(&lcnt[myp[j]], 1);
            int pos = lbase[myp[j]] + r;
            if (pos < pcap) pairs[(size_t)myp[j] * pcap + pos] = make_int2(myd[j], mys[j]);
        }
    }
}

// ---------------- CSR pass 2: one block per partition — deg count, scan, scatter ----------------
__global__ __launch_bounds__(256) void csr_kernel(
    const int2* __restrict__ pairs, int pcap, const int* __restrict__ pcnt,
    int* __restrict__ rowptr, int* __restrict__ col, int N, int chunk, int Etot)
{
    __shared__ int ldeg[NPART];
    __shared__ int wtmp[4];
    __shared__ int sh_pbase;
    int p = blockIdx.x;
    int lo = p * chunk;
    int hi = min(lo + chunk, N);
    int len = max(hi - lo, 0);
    int tid = threadIdx.x;
    int lane = tid & 63, wv = tid >> 6;

    {
        int v = pcnt[tid];
        int inc = v;
#pragma unroll
        for (int m = 1; m < 64; m <<= 1) {
            int t = __shfl_up(inc, m, 64);
            if (lane >= m) inc += t;
        }
        if (lane == 63) wtmp[wv] = inc;
        __syncthreads();
        int woff = 0;
        for (int w = 0; w < wv; ++w) woff += wtmp[w];
        if (tid == p) sh_pbase = inc - v + woff;
        ldeg[tid] = 0;
        __syncthreads();
    }

    int cnt = min(pcnt[p], pcap);
    const int2* pp = pairs + (size_t)p * pcap;
    for (int i = tid; i < cnt; i += 256) {
        atomicAdd(&ldeg[pp[i].x - lo], 1);
    }
    __syncthreads();

    int v = (tid < len) ? ldeg[tid] : 0;
    int inc = v;
#pragma unroll
    for (int m = 1; m < 64; m <<= 1) {
        int t = __shfl_up(inc, m, 64);
        if (lane >= m) inc += t;
    }
    if (lane == 63) wtmp[wv] = inc;
    __syncthreads();
    int woff = 0;
    for (int w = 0; w < wv; ++w) woff += wtmp[w];
    int excl = inc - v + woff;
    int base = sh_pbase;
    __syncthreads();
    if (tid < len) {
        rowptr[lo + tid] = base + excl;
        ldeg[tid] = base + excl;
    }
    if (p == NPART - 1 && tid == 0) rowptr[N] = Etot;
    __syncthreads();

    for (int i = tid; i < cnt; i += 256) {
        int2 e = pp[i];
        int pos = atomicAdd(&ldeg[e.x - lo], 1);
        col[pos] = e.y;
    }
}

// ---------------- GAT layer-1 aggregate + BN1 + ELU + GEMM2 + layer-2 scores (fused) ----------------
// Wave = 4 groups x 16 lanes; group g takes edges start+g, +4,... Lane (g,q) owns channels 8q..8q+7.
// Epilogue: lanes<16 do BN+ELU -> LDS row broadcast -> all 64 lanes compute h2 = row @ W2^T,
// then layer-2 attention scores and fp16 h2 write. hbn1 never hits memory.
__global__ __launch_bounds__(256) void agg1_kernel(
    const __half2* __restrict__ h1h, const float* __restrict__ ssrc1, const float* __restrict__ sdst1,
    const int* __restrict__ rowptr, const int* __restrict__ col,
    const float* __restrict__ b1, const float* __restrict__ g1, const float* __restrict__ be1,
    const float* __restrict__ mu1, const float* __restrict__ var1,
    const float* __restrict__ W2, const float* __restrict__ asrc2, const float* __restrict__ adst2,
    __half2* __restrict__ h2h, float* __restrict__ ssrc2, float* __restrict__ sdst2, int n)
{
    __shared__ float W2s[32 * 129];   // [c2][k], stride 129: conflict-free col reads
    __shared__ float rows[4][128];    // per-wave hbn1 row broadcast
    int tid = threadIdx.x;
    for (int i = tid; i < 32 * 128; i += 256) {
        int c = i >> 7, k = i & 127;
        W2s[c * 129 + k] = W2[i];
    }
    __syncthreads();

    int node = blockIdx.x * 4 + (tid >> 6);
    int lane = tid & 63;
    int wv = tid >> 6;
    if (node >= n) return;
    int start = rowptr[node], end = rowptr[node + 1];
    int g = lane >> 4;          // edge group
    int q = lane & 15;          // channel quad
    int hd = q >> 2;            // head of my 8 channels
    float sdh = sdst1[node * 4 + hd];

    float acc[8] = {0.f, 0.f, 0.f, 0.f, 0.f, 0.f, 0.f, 0.f};
    float dn = 0.f;
#pragma unroll 2
    for (int j = start + g; j < end; j += 4) {
        int s = col[j];
        float e = ssrc1[s * 4 + hd] + sdh;
        e = (e > 0.f) ? e : NEG * e;
        float w = __expf(e);
        dn += w;
        float4 hv = *(const float4*)((const char*)(h1h + (size_t)s * 64) + 16 * q);
        const __half2* hp = (const __half2*)&hv;
#pragma unroll
        for (int t = 0; t < 4; ++t) {
            float2 f = __half22float2(hp[t]);
            acc[2 * t]     += w * f.x;
            acc[2 * t + 1] += w * f.y;
        }
    }
#pragma unroll
    for (int m = 16; m <= 32; m <<= 1) {
        dn += __shfl_xor(dn, m, 64);
#pragma unroll
        for (int t = 0; t < 8; ++t) acc[t] += __shfl_xor(acc[t], m, 64);
    }
    // BN1 + ELU on lanes 0-15 (8 channels each), broadcast via LDS (intra-wave, no barrier needed)
    if (lane < 16) {
        float iv = 1.f / dn;
        int c = 8 * q;
        float4 b0 = *(const float4*)(b1 + c),   b4 = *(const float4*)(b1 + c + 4);
        float4 g0 = *(const float4*)(g1 + c),   g4 = *(const float4*)(g1 + c + 4);
        float4 e0 = *(const float4*)(be1 + c),  e4 = *(const float4*)(be1 + c + 4);
        float4 m0 = *(const float4*)(mu1 + c),  m4 = *(const float4*)(mu1 + c + 4);
        float4 v0 = *(const float4*)(var1 + c), v4 = *(const float4*)(var1 + c + 4);
        const float* bp = (const float*)&b0;  const float* bp4 = (const float*)&b4;
        const float* gp = (const float*)&g0;  const float* gp4 = (const float*)&g4;
        const float* ep = (const float*)&e0;  const float* ep4 = (const float*)&e4;
        const float* mp = (const float*)&m0;  const float* mp4 = (const float*)&m4;
        const float* vp = (const float*)&v0;  const float* vp4 = (const float*)&v4;
        float outv[8];
#pragma unroll
        for (int t = 0; t < 4; ++t) {
            float u = acc[t] * iv + bp[t];
            u = (u - mp[t]) * (gp[t] * rsqrtf(vp[t] + BNEPS)) + ep[t];
            outv[t] = (u > 0.f) ? u : (__expf(u) - 1.f);
        }
#pragma unroll
        for (int t = 0; t < 4; ++t) {
            float u = acc[4 + t] * iv + bp4[t];
            u = (u - mp4[t]) * (gp4[t] * rsqrtf(vp4[t] + BNEPS)) + ep4[t];
            outv[4 + t] = (u > 0.f) ? u : (__expf(u) - 1.f);
        }
        *(float4*)&rows[wv][c]     = make_float4(outv[0], outv[1], outv[2], outv[3]);
        *(float4*)&rows[wv][c + 4] = make_float4(outv[4], outv[5], outv[6], outv[7]);
    }
    // GEMM2: h2[o] = sum_k row[k] * W2[o][k]; lane -> (o = lane&31, half = lane>>5)
    int o = lane & 31, hf = lane >> 5;
    const float* rw = &rows[wv][hf * 64];
    const float* wp = &W2s[o * 129 + hf * 64];
    float a = 0.f;
#pragma unroll
    for (int k = 0; k < 64; ++k) a += rw[k] * wp[k];
    a += __shfl_xor(a, 32, 64);          // lanes 0-31 hold h2[o] (32-63 duplicates)
    // scores + fp16 write (lanes 0-31)
    float ts = a * asrc2[o];
    float td = a * adst2[o];
#pragma unroll
    for (int m = 1; m <= 16; m <<= 1) {
        ts += __shfl_xor(ts, m, 64);
        td += __shfl_xor(td, m, 64);
    }
    if (lane == 0) { ssrc2[node] = ts; sdst2[node] = td; }
    float aodd = __shfl_xor(a, 1, 64);
    if (lane < 32 && (lane & 1) == 0)
        h2h[(size_t)node * 16 + (o >> 1)] = __floats2half2_rn(a, aodd);
}

// ---------------- GAT layer-2: aggregate + BN2 + ELU + classifier ----------------
__global__ __launch_bounds__(256) void agg2_kernel(
    const __half2* __restrict__ h2h, const float* __restrict__ ssrc2, const float* __restrict__ sdst2,
    const int* __restrict__ rowptr, const int* __restrict__ col,
    const float* __restrict__ b2, const float* __restrict__ g2, const float* __restrict__ be2,
    const float* __restrict__ mu2, const float* __restrict__ var2,
    const float* __restrict__ Wc, const float* __restrict__ bc,
    float* __restrict__ out, int n)
{
    int node = blockIdx.x * 4 + (threadIdx.x >> 6);
    int lane = threadIdx.x & 63;
    if (node >= n) return;
    int start = rowptr[node], end = rowptr[node + 1];
    int cp = lane & 15, sub = lane >> 4;
    float sd = sdst2[node];
    float accx = 0.f, accy = 0.f, dn = 0.f;
    for (int j = start + sub; j < end; j += 4) {
        int s = col[j];
        float e = ssrc2[s] + sd;
        e = (e > 0.f) ? e : NEG * e;
        float w = __expf(e);
        dn += w;
        float2 hf = __half22float2(h2h[(size_t)s * 16 + cp]);
        accx += w * hf.x;
        accy += w * hf.y;
    }
    accx += __shfl_xor(accx, 16, 64); accx += __shfl_xor(accx, 32, 64);
    accy += __shfl_xor(accy, 16, 64); accy += __shfl_xor(accy, 32, 64);
    dn   += __shfl_xor(dn,   16, 64); dn   += __shfl_xor(dn,   32, 64);
    float iv = 1.f / dn;
    int c0 = 2 * cp, c1 = c0 + 1;
    float v0 = accx * iv + b2[c0];
    v0 = (v0 - mu2[c0]) * (g2[c0] * rsqrtf(var2[c0] + BNEPS)) + be2[c0];
    v0 = (v0 > 0.f) ? v0 : (__expf(v0) - 1.f);
    float v1 = accy * iv + b2[c1];
    v1 = (v1 - mu2[c1]) * (g2[c1] * rsqrtf(var2[c1] + BNEPS)) + be2[c1];
    v1 = (v1 > 0.f) ? v1 : (__expf(v1) - 1.f);
#pragma unroll
    for (int rr = 0; rr < 3; ++rr) {
        int o = sub + rr * 4;
        float t = 0.f;
        if (o < 10) t = v0 * Wc[o * 32 + c0] + v1 * Wc[o * 32 + c1];
#pragma unroll
        for (int m = 8; m >= 1; m >>= 1) t += __shfl_xor(t, m, 64);
        if (cp == 0 && o < 10) out[(size_t)node * 10 + o] = t + bc[o];
    }
}

extern "C" void kernel_launch(void* const* d_in, const int* in_sizes, int n_in,
                              void* d_out, int out_size, void* d_ws, size_t ws_size,
                              hipStream_t stream)
{
    const float* x     = (const float*)d_in[0];
    const int*   ei    = (const int*)d_in[1];
    const float* W1    = (const float*)d_in[2];
    const float* asrc1 = (const float*)d_in[3];
    const float* adst1 = (const float*)d_in[4];
    const float* b1    = (const float*)d_in[5];
    const float* g1    = (const float*)d_in[6];
    const float* be1   = (const float*)d_in[7];
    const float* mu1   = (const float*)d_in[8];
    const float* var1  = (const float*)d_in[9];
    const float* W2    = (const float*)d_in[10];
    const float* asrc2 = (const float*)d_in[11];
    const float* adst2 = (const float*)d_in[12];
    const float* b2    = (const float*)d_in[13];
    const float* g2    = (const float*)d_in[14];
    const float* be2   = (const float*)d_in[15];
    const float* mu2   = (const float*)d_in[16];
    const float* var2  = (const float*)d_in[17];
    const float* Wc    = (const float*)d_in[18];
    const float* bc    = (const float*)d_in[19];

    int N_ = in_sizes[0] / 128;
    int E_ = in_sizes[1] / 2;
    int Etot = E_ + N_;
    const int* srcp = ei;
    const int* dstp = ei + E_;
    int chunk = (N_ + NPART - 1) / NPART;
    int pcap = Etot / NPART + 1024;

    char* ws = (char*)d_ws;
    size_t off = 0;
    auto alloc = [&](size_t bytes) -> char* {
        char* p = ws + off;
        off += (bytes + 255) & ~(size_t)255;
        return p;
    };
    __half2* h1h   = (__half2*)alloc((size_t)N_ * 64 * 4);
    __half2* h2h   = (__half2*)alloc((size_t)N_ * 16 * 4);
    float*   ssrc1 = (float*)alloc((size_t)N_ * 4 * 4);
    float*   sdst1 = (float*)alloc((size_t)N_ * 4 * 4);
    float*   ssrc2 = (float*)alloc((size_t)N_ * 4);
    float*   sdst2 = (float*)alloc((size_t)N_ * 4);
    int*     rowptr= (int*)alloc((size_t)(N_ + 1) * 4);
    int*     col   = (int*)alloc((size_t)Etot * 4);
    int2*    pairs = (int2*)alloc((size_t)NPART * pcap * 8);
    int*     pcur  = (int*)alloc((size_t)NPART * 4);

    hipMemsetAsync(pcur, 0, NPART * 4, stream);
    gemm1_kernel<<<(N_ + 63) / 64, 256, 0, stream>>>(x, W1, asrc1, adst1, h1h, ssrc1, sdst1, N_);
    int per_block = 256 * 8;
    part_kernel<<<(Etot + per_block - 1) / per_block, 256, 0, stream>>>(
        srcp, dstp, E_, Etot, chunk, pairs, pcap, pcur);
    csr_kernel<<<NPART, 256, 0, stream>>>(pairs, pcap, pcur, rowptr, col, N_, chunk, Etot);
    agg1_kernel<<<(N_ + 3) / 4, 256, 0, stream>>>(h1h, ssrc1, sdst1, rowptr, col,
                                                  b1, g1, be1, mu1, var1,
                                                  W2, asrc2, adst2, h2h, ssrc2, sdst2, N_);
    agg2_kernel<<<(N_ + 3) / 4, 256, 0, stream>>>(h2h, ssrc2, sdst2, rowptr, col,
                                                  b2, g2, be2, mu2, var2, Wc, bc, (float*)d_out, N_);
}

// Round 10
// 141.946 us; speedup vs baseline: 1.2412x; 1.1987x over previous
//
#include <hip/hip_runtime.h>
#include <hip/hip_fp16.h>

#define NEG 0.2f
#define BNEPS 1e-5f
#define NPART 256

typedef _Float16 f16x8 __attribute__((ext_vector_type(8)));
typedef float f32x4 __attribute__((ext_vector_type(4)));

// ---------------- GEMM1 (MFMA): h1 = x @ W1^T [N,128] fp16 + s_src1/s_dst1 [N,4] ----------------
// Block 256 = 4 waves; wave computes 16 rows x 128 cols via 8 col-tiles x 4 k-steps of 16x16x32.
// A: row=lane&15, k=8*(lane>>4)+i.  B[k][c]: col c=16t+(lane&15), same k.  D: col=lane&15, row=4*(lane>>4)+i.
__global__ __launch_bounds__(256) void gemm1_kernel(
    const float* __restrict__ x, const float* __restrict__ W1,
    const float* __restrict__ asrc, const float* __restrict__ adst,
    __half2* __restrict__ h1h, float* __restrict__ ssrc1, float* __restrict__ sdst1, int n)
{
    __shared__ _Float16 Ws[128 * 136];       // W1 [c][k], stride 136
    __shared__ _Float16 Xs[4 * 16 * 136];    // per-wave 16-row x-tile [row][k]
    int tid = threadIdx.x, lane = tid & 63, wv = tid >> 6;

    // stage W1 -> f16 LDS
    {
        int c = tid >> 1, kh = (tid & 1) * 64;
        const float4* src = (const float4*)(W1 + (size_t)c * 128 + kh);
        _Float16* dst = &Ws[c * 136 + kh];
#pragma unroll
        for (int i = 0; i < 16; ++i) {
            float4 v = src[i];
            dst[4 * i + 0] = (_Float16)v.x; dst[4 * i + 1] = (_Float16)v.y;
            dst[4 * i + 2] = (_Float16)v.z; dst[4 * i + 3] = (_Float16)v.w;
        }
    }
    // stage 16 x-rows per wave -> f16 LDS
    int rbase = blockIdx.x * 64 + wv * 16;
    {
        int r = lane >> 2, k0 = (lane & 3) * 32;
        int grow = rbase + r;
        _Float16* dst = &Xs[(wv * 16 + r) * 136 + k0];
        if (grow < n) {
            const float4* src = (const float4*)(x + (size_t)grow * 128 + k0);
#pragma unroll
            for (int i = 0; i < 8; ++i) {
                float4 v = src[i];
                dst[4 * i + 0] = (_Float16)v.x; dst[4 * i + 1] = (_Float16)v.y;
                dst[4 * i + 2] = (_Float16)v.z; dst[4 * i + 3] = (_Float16)v.w;
            }
        } else {
#pragma unroll
            for (int i = 0; i < 32; ++i) dst[i] = (_Float16)0.f;
        }
    }
    __syncthreads();

    int q = lane & 15, kg = lane >> 4;
    f32x4 acc[8];
#pragma unroll
    for (int t = 0; t < 8; ++t) acc[t] = (f32x4){0.f, 0.f, 0.f, 0.f};
#pragma unroll
    for (int kt = 0; kt < 4; ++kt) {
        f16x8 a = *(const f16x8*)&Xs[(wv * 16 + q) * 136 + kt * 32 + kg * 8];
#pragma unroll
        for (int t = 0; t < 8; ++t) {
            f16x8 b = *(const f16x8*)&Ws[(t * 16 + q) * 136 + kt * 32 + kg * 8];
            acc[t] = __builtin_amdgcn_mfma_f32_16x16x32_f16(a, b, acc[t], 0, 0, 0);
        }
    }

    // attention scores from fragments: head of col c=16t+q is t>>1
    float sp[4][4], sd[4][4];
#pragma unroll
    for (int i = 0; i < 4; ++i)
#pragma unroll
        for (int h = 0; h < 4; ++h) { sp[i][h] = 0.f; sd[i][h] = 0.f; }
#pragma unroll
    for (int t = 0; t < 8; ++t) {
        float as = asrc[t * 16 + q], ad = adst[t * 16 + q];
        int h = t >> 1;
#pragma unroll
        for (int i = 0; i < 4; ++i) {
            sp[i][h] += acc[t][i] * as;
            sd[i][h] += acc[t][i] * ad;
        }
    }
#pragma unroll
    for (int m = 1; m <= 8; m <<= 1) {
#pragma unroll
        for (int i = 0; i < 4; ++i)
#pragma unroll
            for (int h = 0; h < 4; ++h) {
                sp[i][h] += __shfl_xor(sp[i][h], m, 64);
                sd[i][h] += __shfl_xor(sd[i][h], m, 64);
            }
    }
    if (q == 0) {
#pragma unroll
        for (int i = 0; i < 4; ++i) {
            int row = rbase + kg * 4 + i;
            if (row < n) {
#pragma unroll
                for (int h = 0; h < 4; ++h) {
                    ssrc1[row * 4 + h] = sp[i][h];
                    sdst1[row * 4 + h] = sd[i][h];
                }
            }
        }
    }

    // transpose D -> LDS (reuse Xs) -> coalesced fp16 global store
    __syncthreads();
#pragma unroll
    for (int t = 0; t < 8; ++t)
#pragma unroll
        for (int i = 0; i < 4; ++i)
            Xs[(wv * 16 + kg * 4 + i) * 136 + t * 16 + q] = (_Float16)acc[t][i];
    __syncthreads();
    {
        int r = lane >> 2, k0 = (lane & 3) * 32;
        int grow = rbase + r;
        if (grow < n) {
            const float4* src = (const float4*)&Xs[(wv * 16 + r) * 136 + k0];
            float4* dst = (float4*)((__half*)h1h + (size_t)grow * 128 + k0);
#pragma unroll
            for (int i = 0; i < 4; ++i) dst[i] = src[i];
        }
    }
}

// ---------------- CSR pass 1: partition edges into 256 dst-range buckets ----------------
__global__ __launch_bounds__(256) void part_kernel(
    const int* __restrict__ srcp, const int* __restrict__ dstp, int E, int Etot, int chunk,
    int2* __restrict__ pairs, int pcap, int* __restrict__ pcur)
{
    __shared__ int lcnt[NPART], lbase[NPART];
    const int PER = 8;
    int t0 = blockIdx.x * 256 * PER;
    int tid = threadIdx.x;
    lcnt[tid] = 0;
    __syncthreads();
    int myd[PER], mys[PER], myp[PER];
#pragma unroll
    for (int j = 0; j < PER; ++j) {
        int i = t0 + j * 256 + tid;
        if (i < Etot) {
            int s, d;
            if (i < E) { s = srcp[i]; d = dstp[i]; } else { s = i - E; d = i - E; }
            myd[j] = d; mys[j] = s; myp[j] = d / chunk;
            atomicAdd(&lcnt[myp[j]], 1);
        } else myp[j] = -1;
    }
    __syncthreads();
    lbase[tid] = atomicAdd(&pcur[tid], lcnt[tid]);
    lcnt[tid] = 0;
    __syncthreads();
#pragma unroll
    for (int j = 0; j < PER; ++j) {
        if (myp[j] >= 0) {
            int r = atomicAdd(&lcnt[myp[j]], 1);
            int pos = lbase[myp[j]] + r;
            if (pos < pcap) pairs[(size_t)myp[j] * pcap + pos] = make_int2(myd[j], mys[j]);
        }
    }
}

// ---------------- CSR pass 2: one block per partition — deg count, scan, scatter ----------------
__global__ __launch_bounds__(256) void csr_kernel(
    const int2* __restrict__ pairs, int pcap, const int* __restrict__ pcnt,
    int* __restrict__ rowptr, int* __restrict__ col, int N, int chunk, int Etot)
{
    __shared__ int ldeg[NPART];
    __shared__ int wtmp[4];
    __shared__ int sh_pbase;
    int p = blockIdx.x;
    int lo = p * chunk;
    int hi = min(lo + chunk, N);
    int len = max(hi - lo, 0);
    int tid = threadIdx.x;
    int lane = tid & 63, wv = tid >> 6;

    {
        int v = pcnt[tid];
        int inc = v;
#pragma unroll
        for (int m = 1; m < 64; m <<= 1) {
            int t = __shfl_up(inc, m, 64);
            if (lane >= m) inc += t;
        }
        if (lane == 63) wtmp[wv] = inc;
        __syncthreads();
        int woff = 0;
        for (int w = 0; w < wv; ++w) woff += wtmp[w];
        if (tid == p) sh_pbase = inc - v + woff;
        ldeg[tid] = 0;
        __syncthreads();
    }

    int cnt = min(pcnt[p], pcap);
    const int2* pp = pairs + (size_t)p * pcap;
    for (int i = tid; i < cnt; i += 256) {
        atomicAdd(&ldeg[pp[i].x - lo], 1);
    }
    __syncthreads();

    int v = (tid < len) ? ldeg[tid] : 0;
    int inc = v;
#pragma unroll
    for (int m = 1; m < 64; m <<= 1) {
        int t = __shfl_up(inc, m, 64);
        if (lane >= m) inc += t;
    }
    if (lane == 63) wtmp[wv] = inc;
    __syncthreads();
    int woff = 0;
    for (int w = 0; w < wv; ++w) woff += wtmp[w];
    int excl = inc - v + woff;
    int base = sh_pbase;
    __syncthreads();
    if (tid < len) {
        rowptr[lo + tid] = base + excl;
        ldeg[tid] = base + excl;
    }
    if (p == NPART - 1 && tid == 0) rowptr[N] = Etot;
    __syncthreads();

    for (int i = tid; i < cnt; i += 256) {
        int2 e = pp[i];
        int pos = atomicAdd(&ldeg[e.x - lo], 1);
        col[pos] = e.y;
    }
}

// ---------------- GAT layer-1: 4-edges-in-flight aggregate + bias + BN1 + ELU (fp16 out) ----------
__global__ __launch_bounds__(256) void agg1_kernel(
    const __half2* __restrict__ h1h, const float* __restrict__ ssrc1, const float* __restrict__ sdst1,
    const int* __restrict__ rowptr, const int* __restrict__ col,
    const float* __restrict__ b1, const float* __restrict__ g1, const float* __restrict__ be1,
    const float* __restrict__ mu1, const float* __restrict__ var1,
    _Float16* __restrict__ hbn1h, int n)
{
    int node = blockIdx.x * 4 + (threadIdx.x >> 6);
    int lane = threadIdx.x & 63;
    if (node >= n) return;
    int start = rowptr[node], end = rowptr[node + 1];
    int g = lane >> 4;          // edge group
    int q = lane & 15;          // channel quad
    int hd = q >> 2;            // head of my 8 channels
    float sdh = sdst1[node * 4 + hd];

    float acc[8] = {0.f, 0.f, 0.f, 0.f, 0.f, 0.f, 0.f, 0.f};
    float dn = 0.f;
#pragma unroll 2
    for (int j = start + g; j < end; j += 4) {
        int s = col[j];
        float e = ssrc1[s * 4 + hd] + sdh;
        e = (e > 0.f) ? e : NEG * e;
        float w = __expf(e);
        dn += w;
        float4 hv = *(const float4*)((const char*)(h1h + (size_t)s * 64) + 16 * q);
        const __half2* hp = (const __half2*)&hv;
#pragma unroll
        for (int t = 0; t < 4; ++t) {
            float2 f = __half22float2(hp[t]);
            acc[2 * t]     += w * f.x;
            acc[2 * t + 1] += w * f.y;
        }
    }
#pragma unroll
    for (int m = 16; m <= 32; m <<= 1) {
        dn += __shfl_xor(dn, m, 64);
#pragma unroll
        for (int t = 0; t < 8; ++t) acc[t] += __shfl_xor(acc[t], m, 64);
    }
    if (lane < 16) {
        float iv = 1.f / dn;
        int c = 8 * q;
        float4 b0 = *(const float4*)(b1 + c),   b4 = *(const float4*)(b1 + c + 4);
        float4 g0 = *(const float4*)(g1 + c),   g4 = *(const float4*)(g1 + c + 4);
        float4 e0 = *(const float4*)(be1 + c),  e4 = *(const float4*)(be1 + c + 4);
        float4 m0 = *(const float4*)(mu1 + c),  m4 = *(const float4*)(mu1 + c + 4);
        float4 v0 = *(const float4*)(var1 + c), v4 = *(const float4*)(var1 + c + 4);
        const float* bp = (const float*)&b0;  const float* bp4 = (const float*)&b4;
        const float* gp = (const float*)&g0;  const float* gp4 = (const float*)&g4;
        const float* ep = (const float*)&e0;  const float* ep4 = (const float*)&e4;
        const float* mp = (const float*)&m0;  const float* mp4 = (const float*)&m4;
        const float* vp = (const float*)&v0;  const float* vp4 = (const float*)&v4;
        f16x8 ov;
#pragma unroll
        for (int t = 0; t < 4; ++t) {
            float u = acc[t] * iv + bp[t];
            u = (u - mp[t]) * (gp[t] * rsqrtf(vp[t] + BNEPS)) + ep[t];
            u = (u > 0.f) ? u : (__expf(u) - 1.f);
            ov[t] = (_Float16)u;
        }
#pragma unroll
        for (int t = 0; t < 4; ++t) {
            float u = acc[4 + t] * iv + bp4[t];
            u = (u - mp4[t]) * (gp4[t] * rsqrtf(vp4[t] + BNEPS)) + ep4[t];
            u = (u > 0.f) ? u : (__expf(u) - 1.f);
            ov[4 + t] = (_Float16)u;
        }
        *(f16x8*)&hbn1h[(size_t)node * 128 + c] = ov;
    }
}

// ---------------- GEMM2 (MFMA): h2 = hbn1 @ W2^T [N,32] fp16 + s_src2/s_dst2 [N] ----------------
__global__ __launch_bounds__(256) void gemm2_kernel(
    const _Float16* __restrict__ hbn1h, const float* __restrict__ W2,
    const float* __restrict__ asrc2, const float* __restrict__ adst2,
    __half2* __restrict__ h2h, float* __restrict__ ssrc2, float* __restrict__ sdst2, int n)
{
    __shared__ _Float16 Ws[32 * 136];
    int tid = threadIdx.x, lane = tid & 63, wv = tid >> 6;
    {
        int c = tid >> 3, k0 = (tid & 7) * 16;
        const float4* src = (const float4*)(W2 + (size_t)c * 128 + k0);
        _Float16* dst = &Ws[c * 136 + k0];
#pragma unroll
        for (int i = 0; i < 4; ++i) {
            float4 v = src[i];
            dst[4 * i + 0] = (_Float16)v.x; dst[4 * i + 1] = (_Float16)v.y;
            dst[4 * i + 2] = (_Float16)v.z; dst[4 * i + 3] = (_Float16)v.w;
        }
    }
    __syncthreads();

    int rbase = blockIdx.x * 64 + wv * 16;
    int q = lane & 15, kg = lane >> 4;
    int arow = min(rbase + q, n - 1);
    f32x4 acc[2];
    acc[0] = (f32x4){0.f, 0.f, 0.f, 0.f};
    acc[1] = (f32x4){0.f, 0.f, 0.f, 0.f};
#pragma unroll
    for (int kt = 0; kt < 4; ++kt) {
        f16x8 a = *(const f16x8*)&hbn1h[(size_t)arow * 128 + kt * 32 + kg * 8];
#pragma unroll
        for (int t = 0; t < 2; ++t) {
            f16x8 b = *(const f16x8*)&Ws[(t * 16 + q) * 136 + kt * 32 + kg * 8];
            acc[t] = __builtin_amdgcn_mfma_f32_16x16x32_f16(a, b, acc[t], 0, 0, 0);
        }
    }

    float sp[4] = {0.f, 0.f, 0.f, 0.f}, sd[4] = {0.f, 0.f, 0.f, 0.f};
#pragma unroll
    for (int t = 0; t < 2; ++t) {
        float as = asrc2[t * 16 + q], ad = adst2[t * 16 + q];
#pragma unroll
        for (int i = 0; i < 4; ++i) {
            sp[i] += acc[t][i] * as;
            sd[i] += acc[t][i] * ad;
        }
    }
#pragma unroll
    for (int m = 1; m <= 8; m <<= 1) {
#pragma unroll
        for (int i = 0; i < 4; ++i) {
            sp[i] += __shfl_xor(sp[i], m, 64);
            sd[i] += __shfl_xor(sd[i], m, 64);
        }
    }
    if (q == 0) {
#pragma unroll
        for (int i = 0; i < 4; ++i) {
            int row = rbase + kg * 4 + i;
            if (row < n) { ssrc2[row] = sp[i]; sdst2[row] = sd[i]; }
        }
    }
    // h2h store: pair adjacent channels via shfl
#pragma unroll
    for (int t = 0; t < 2; ++t) {
#pragma unroll
        for (int i = 0; i < 4; ++i) {
            float v = acc[t][i];
            float vn = __shfl_xor(v, 1, 64);
            if ((q & 1) == 0) {
                int row = rbase + kg * 4 + i;
                if (row < n)
                    h2h[(size_t)row * 16 + t * 8 + (q >> 1)] = __floats2half2_rn(v, vn);
            }
        }
    }
}

// ---------------- GAT layer-2: aggregate + BN2 + ELU + classifier ----------------
__global__ __launch_bounds__(256) void agg2_kernel(
    const __half2* __restrict__ h2h, const float* __restrict__ ssrc2, const float* __restrict__ sdst2,
    const int* __restrict__ rowptr, const int* __restrict__ col,
    const float* __restrict__ b2, const float* __restrict__ g2, const float* __restrict__ be2,
    const float* __restrict__ mu2, const float* __restrict__ var2,
    const float* __restrict__ Wc, const float* __restrict__ bc,
    float* __restrict__ out, int n)
{
    int node = blockIdx.x * 4 + (threadIdx.x >> 6);
    int lane = threadIdx.x & 63;
    if (node >= n) return;
    int start = rowptr[node], end = rowptr[node + 1];
    int cp = lane & 15, sub = lane >> 4;
    float sd = sdst2[node];
    float accx = 0.f, accy = 0.f, dn = 0.f;
    for (int j = start + sub; j < end; j += 4) {
        int s = col[j];
        float e = ssrc2[s] + sd;
        e = (e > 0.f) ? e : NEG * e;
        float w = __expf(e);
        dn += w;
        float2 hf = __half22float2(h2h[(size_t)s * 16 + cp]);
        accx += w * hf.x;
        accy += w * hf.y;
    }
    accx += __shfl_xor(accx, 16, 64); accx += __shfl_xor(accx, 32, 64);
    accy += __shfl_xor(accy, 16, 64); accy += __shfl_xor(accy, 32, 64);
    dn   += __shfl_xor(dn,   16, 64); dn   += __shfl_xor(dn,   32, 64);
    float iv = 1.f / dn;
    int c0 = 2 * cp, c1 = c0 + 1;
    float v0 = accx * iv + b2[c0];
    v0 = (v0 - mu2[c0]) * (g2[c0] * rsqrtf(var2[c0] + BNEPS)) + be2[c0];
    v0 = (v0 > 0.f) ? v0 : (__expf(v0) - 1.f);
    float v1 = accy * iv + b2[c1];
    v1 = (v1 - mu2[c1]) * (g2[c1] * rsqrtf(var2[c1] + BNEPS)) + be2[c1];
    v1 = (v1 > 0.f) ? v1 : (__expf(v1) - 1.f);
#pragma unroll
    for (int rr = 0; rr < 3; ++rr) {
        int o = sub + rr * 4;
        float t = 0.f;
        if (o < 10) t = v0 * Wc[o * 32 + c0] + v1 * Wc[o * 32 + c1];
#pragma unroll
        for (int m = 8; m >= 1; m >>= 1) t += __shfl_xor(t, m, 64);
        if (cp == 0 && o < 10) out[(size_t)node * 10 + o] = t + bc[o];
    }
}

extern "C" void kernel_launch(void* const* d_in, const int* in_sizes, int n_in,
                              void* d_out, int out_size, void* d_ws, size_t ws_size,
                              hipStream_t stream)
{
    const float* x     = (const float*)d_in[0];
    const int*   ei    = (const int*)d_in[1];
    const float* W1    = (const float*)d_in[2];
    const float* asrc1 = (const float*)d_in[3];
    const float* adst1 = (const float*)d_in[4];
    const float* b1    = (const float*)d_in[5];
    const float* g1    = (const float*)d_in[6];
    const float* be1   = (const float*)d_in[7];
    const float* mu1   = (const float*)d_in[8];
    const float* var1  = (const float*)d_in[9];
    const float* W2    = (const float*)d_in[10];
    const float* asrc2 = (const float*)d_in[11];
    const float* adst2 = (const float*)d_in[12];
    const float* b2    = (const float*)d_in[13];
    const float* g2    = (const float*)d_in[14];
    const float* be2   = (const float*)d_in[15];
    const float* mu2   = (const float*)d_in[16];
    const float* var2  = (const float*)d_in[17];
    const float* Wc    = (const float*)d_in[18];
    const float* bc    = (const float*)d_in[19];

    int N_ = in_sizes[0] / 128;
    int E_ = in_sizes[1] / 2;
    int Etot = E_ + N_;
    const int* srcp = ei;
    const int* dstp = ei + E_;
    int chunk = (N_ + NPART - 1) / NPART;
    int pcap = Etot / NPART + 1024;

    char* ws = (char*)d_ws;
    size_t off = 0;
    auto alloc = [&](size_t bytes) -> char* {
        char* p = ws + off;
        off += (bytes + 255) & ~(size_t)255;
        return p;
    };
    __half2*   h1h   = (__half2*)alloc((size_t)N_ * 64 * 4);
    _Float16*  hbn1h = (_Float16*)alloc((size_t)N_ * 128 * 2);
    __half2*   h2h   = (__half2*)alloc((size_t)N_ * 16 * 4);
    float*     ssrc1 = (float*)alloc((size_t)N_ * 4 * 4);
    float*     sdst1 = (float*)alloc((size_t)N_ * 4 * 4);
    float*     ssrc2 = (float*)alloc((size_t)N_ * 4);
    float*     sdst2 = (float*)alloc((size_t)N_ * 4);
    int*       rowptr= (int*)alloc((size_t)(N_ + 1) * 4);
    int*       col   = (int*)alloc((size_t)Etot * 4);
    int2*      pairs = (int2*)alloc((size_t)NPART * pcap * 8);
    int*       pcur  = (int*)alloc((size_t)NPART * 4);

    hipMemsetAsync(pcur, 0, NPART * 4, stream);
    gemm1_kernel<<<(N_ + 63) / 64, 256, 0, stream>>>(x, W1, asrc1, adst1, h1h, ssrc1, sdst1, N_);
    int per_block = 256 * 8;
    part_kernel<<<(Etot + per_block - 1) / per_block, 256, 0, stream>>>(
        srcp, dstp, E_, Etot, chunk, pairs, pcap, pcur);
    csr_kernel<<<NPART, 256, 0, stream>>>(pairs, pcap, pcur, rowptr, col, N_, chunk, Etot);
    agg1_kernel<<<(N_ + 3) / 4, 256, 0, stream>>>(h1h, ssrc1, sdst1, rowptr, col,
                                                  b1, g1, be1, mu1, var1, hbn1h, N_);
    gemm2_kernel<<<(N_ + 63) / 64, 256, 0, stream>>>(hbn1h, W2, asrc2, adst2, h2h, ssrc2, sdst2, N_);
    agg2_kernel<<<(N_ + 3) / 4, 256, 0, stream>>>(h2h, ssrc2, sdst2, rowptr, col,
                                                  b2, g2, be2, mu2, var2, Wc, bc, (float*)d_out, N_);
}

// Round 11
// 116.359 us; speedup vs baseline: 1.5142x; 1.2199x over previous
//
#include <hip/hip_runtime.h>
#include <hip/hip_fp16.h>

#define NEG 0.2f
#define BNEPS 1e-5f
#define NPART 256

typedef _Float16 f16x8 __attribute__((ext_vector_type(8)));
typedef float f32x4 __attribute__((ext_vector_type(4)));

// ---------------- Fused GEMM1 (MFMA) + edge partition ----------------
// blocks [0, gemm_blocks): h1 = x @ W1^T [N,128] fp16 + s_src1/s_dst1 [N,4]
// blocks [gemm_blocks, ...): partition edges into 256 dst-range buckets (runs concurrently)
__global__ __launch_bounds__(256) void gemm1_part_kernel(
    const float* __restrict__ x, const float* __restrict__ W1,
    const float* __restrict__ asrc, const float* __restrict__ adst,
    __half2* __restrict__ h1h, float* __restrict__ ssrc1, float* __restrict__ sdst1,
    int n, int gemm_blocks,
    const int* __restrict__ srcp, const int* __restrict__ dstp, int E, int Etot, int chunk,
    int2* __restrict__ pairs, int pcap, int* __restrict__ pcur)
{
    __shared__ _Float16 Ws[128 * 136];       // gemm: W1 [c][k] | part: reused as int counters
    __shared__ _Float16 Xs[4 * 16 * 136];    // gemm: per-wave x-tiles
    int tid = threadIdx.x, lane = tid & 63, wv = tid >> 6;

    if (blockIdx.x >= gemm_blocks) {
        // ---------------- part body ----------------
        int* lcnt = (int*)Ws;
        int* lbase = (int*)Ws + 256;
        const int PER = 8;
        int t0 = (blockIdx.x - gemm_blocks) * 256 * PER;
        lcnt[tid] = 0;
        __syncthreads();
        int myd[PER], mys[PER], myp[PER];
#pragma unroll
        for (int j = 0; j < PER; ++j) {
            int i = t0 + j * 256 + tid;
            if (i < Etot) {
                int s, d;
                if (i < E) { s = srcp[i]; d = dstp[i]; } else { s = i - E; d = i - E; }
                myd[j] = d; mys[j] = s; myp[j] = d / chunk;
                atomicAdd(&lcnt[myp[j]], 1);
            } else myp[j] = -1;
        }
        __syncthreads();
        lbase[tid] = atomicAdd(&pcur[tid], lcnt[tid]);
        lcnt[tid] = 0;
        __syncthreads();
#pragma unroll
        for (int j = 0; j < PER; ++j) {
            if (myp[j] >= 0) {
                int r = atomicAdd(&lcnt[myp[j]], 1);
                int pos = lbase[myp[j]] + r;
                if (pos < pcap) pairs[(size_t)myp[j] * pcap + pos] = make_int2(myd[j], mys[j]);
            }
        }
        return;
    }

    // ---------------- gemm1 body ----------------
    {
        int c = tid >> 1, kh = (tid & 1) * 64;
        const float4* src = (const float4*)(W1 + (size_t)c * 128 + kh);
        _Float16* dst = &Ws[c * 136 + kh];
#pragma unroll
        for (int i = 0; i < 16; ++i) {
            float4 v = src[i];
            dst[4 * i + 0] = (_Float16)v.x; dst[4 * i + 1] = (_Float16)v.y;
            dst[4 * i + 2] = (_Float16)v.z; dst[4 * i + 3] = (_Float16)v.w;
        }
    }
    int rbase = blockIdx.x * 64 + wv * 16;
    {
        int r = lane >> 2, k0 = (lane & 3) * 32;
        int grow = rbase + r;
        _Float16* dst = &Xs[(wv * 16 + r) * 136 + k0];
        if (grow < n) {
            const float4* src = (const float4*)(x + (size_t)grow * 128 + k0);
#pragma unroll
            for (int i = 0; i < 8; ++i) {
                float4 v = src[i];
                dst[4 * i + 0] = (_Float16)v.x; dst[4 * i + 1] = (_Float16)v.y;
                dst[4 * i + 2] = (_Float16)v.z; dst[4 * i + 3] = (_Float16)v.w;
            }
        } else {
#pragma unroll
            for (int i = 0; i < 32; ++i) dst[i] = (_Float16)0.f;
        }
    }
    __syncthreads();

    int q = lane & 15, kg = lane >> 4;
    f32x4 acc[8];
#pragma unroll
    for (int t = 0; t < 8; ++t) acc[t] = (f32x4){0.f, 0.f, 0.f, 0.f};
#pragma unroll
    for (int kt = 0; kt < 4; ++kt) {
        f16x8 a = *(const f16x8*)&Xs[(wv * 16 + q) * 136 + kt * 32 + kg * 8];
#pragma unroll
        for (int t = 0; t < 8; ++t) {
            f16x8 b = *(const f16x8*)&Ws[(t * 16 + q) * 136 + kt * 32 + kg * 8];
            acc[t] = __builtin_amdgcn_mfma_f32_16x16x32_f16(a, b, acc[t], 0, 0, 0);
        }
    }

    float sp[4][4], sd[4][4];
#pragma unroll
    for (int i = 0; i < 4; ++i)
#pragma unroll
        for (int h = 0; h < 4; ++h) { sp[i][h] = 0.f; sd[i][h] = 0.f; }
#pragma unroll
    for (int t = 0; t < 8; ++t) {
        float as = asrc[t * 16 + q], ad = adst[t * 16 + q];
        int h = t >> 1;
#pragma unroll
        for (int i = 0; i < 4; ++i) {
            sp[i][h] += acc[t][i] * as;
            sd[i][h] += acc[t][i] * ad;
        }
    }
#pragma unroll
    for (int m = 1; m <= 8; m <<= 1) {
#pragma unroll
        for (int i = 0; i < 4; ++i)
#pragma unroll
            for (int h = 0; h < 4; ++h) {
                sp[i][h] += __shfl_xor(sp[i][h], m, 64);
                sd[i][h] += __shfl_xor(sd[i][h], m, 64);
            }
    }
    if (q == 0) {
#pragma unroll
        for (int i = 0; i < 4; ++i) {
            int row = rbase + kg * 4 + i;
            if (row < n) {
#pragma unroll
                for (int h = 0; h < 4; ++h) {
                    ssrc1[row * 4 + h] = sp[i][h];
                    sdst1[row * 4 + h] = sd[i][h];
                }
            }
        }
    }

    __syncthreads();
#pragma unroll
    for (int t = 0; t < 8; ++t)
#pragma unroll
        for (int i = 0; i < 4; ++i)
            Xs[(wv * 16 + kg * 4 + i) * 136 + t * 16 + q] = (_Float16)acc[t][i];
    __syncthreads();
    {
        int r = lane >> 2, k0 = (lane & 3) * 32;
        int grow = rbase + r;
        if (grow < n) {
            const float4* src = (const float4*)&Xs[(wv * 16 + r) * 136 + k0];
            float4* dst = (float4*)((__half*)h1h + (size_t)grow * 128 + k0);
#pragma unroll
            for (int i = 0; i < 4; ++i) dst[i] = src[i];
        }
    }
}

// ---------------- CSR pass 2: one block per partition — deg count, scan, scatter ----------------
__global__ __launch_bounds__(256) void csr_kernel(
    const int2* __restrict__ pairs, int pcap, const int* __restrict__ pcnt,
    int* __restrict__ rowptr, int* __restrict__ col, int N, int chunk, int Etot)
{
    __shared__ int ldeg[NPART];
    __shared__ int wtmp[4];
    __shared__ int sh_pbase;
    int p = blockIdx.x;
    int lo = p * chunk;
    int hi = min(lo + chunk, N);
    int len = max(hi - lo, 0);
    int tid = threadIdx.x;
    int lane = tid & 63, wv = tid >> 6;

    {
        int v = pcnt[tid];
        int inc = v;
#pragma unroll
        for (int m = 1; m < 64; m <<= 1) {
            int t = __shfl_up(inc, m, 64);
            if (lane >= m) inc += t;
        }
        if (lane == 63) wtmp[wv] = inc;
        __syncthreads();
        int woff = 0;
        for (int w = 0; w < wv; ++w) woff += wtmp[w];
        if (tid == p) sh_pbase = inc - v + woff;
        ldeg[tid] = 0;
        __syncthreads();
    }

    int cnt = min(pcnt[p], pcap);
    const int2* pp = pairs + (size_t)p * pcap;
    for (int i = tid; i < cnt; i += 256) {
        atomicAdd(&ldeg[pp[i].x - lo], 1);
    }
    __syncthreads();

    int v = (tid < len) ? ldeg[tid] : 0;
    int inc = v;
#pragma unroll
    for (int m = 1; m < 64; m <<= 1) {
        int t = __shfl_up(inc, m, 64);
        if (lane >= m) inc += t;
    }
    if (lane == 63) wtmp[wv] = inc;
    __syncthreads();
    int woff = 0;
    for (int w = 0; w < wv; ++w) woff += wtmp[w];
    int excl = inc - v + woff;
    int base = sh_pbase;
    __syncthreads();
    if (tid < len) {
        rowptr[lo + tid] = base + excl;
        ldeg[tid] = base + excl;
    }
    if (p == NPART - 1 && tid == 0) rowptr[N] = Etot;
    __syncthreads();

    for (int i = tid; i < cnt; i += 256) {
        int2 e = pp[i];
        int pos = atomicAdd(&ldeg[e.x - lo], 1);
        col[pos] = e.y;
    }
}

// ---------------- GAT layer-1: 4-edges-in-flight aggregate + bias + BN1 + ELU (fp16 out) ----------
__global__ __launch_bounds__(256) void agg1_kernel(
    const __half2* __restrict__ h1h, const float* __restrict__ ssrc1, const float* __restrict__ sdst1,
    const int* __restrict__ rowptr, const int* __restrict__ col,
    const float* __restrict__ b1, const float* __restrict__ g1, const float* __restrict__ be1,
    const float* __restrict__ mu1, const float* __restrict__ var1,
    _Float16* __restrict__ hbn1h, int n)
{
    int node = blockIdx.x * 4 + (threadIdx.x >> 6);
    int lane = threadIdx.x & 63;
    if (node >= n) return;
    int start = rowptr[node], end = rowptr[node + 1];
    int g = lane >> 4;          // edge group
    int q = lane & 15;          // channel quad
    int hd = q >> 2;            // head of my 8 channels
    float sdh = sdst1[node * 4 + hd];

    float acc[8] = {0.f, 0.f, 0.f, 0.f, 0.f, 0.f, 0.f, 0.f};
    float dn = 0.f;
#pragma unroll 2
    for (int j = start + g; j < end; j += 4) {
        int s = col[j];
        float e = ssrc1[s * 4 + hd] + sdh;
        e = (e > 0.f) ? e : NEG * e;
        float w = __expf(e);
        dn += w;
        float4 hv = *(const float4*)((const char*)(h1h + (size_t)s * 64) + 16 * q);
        const __half2* hp = (const __half2*)&hv;
#pragma unroll
        for (int t = 0; t < 4; ++t) {
            float2 f = __half22float2(hp[t]);
            acc[2 * t]     += w * f.x;
            acc[2 * t + 1] += w * f.y;
        }
    }
#pragma unroll
    for (int m = 16; m <= 32; m <<= 1) {
        dn += __shfl_xor(dn, m, 64);
#pragma unroll
        for (int t = 0; t < 8; ++t) acc[t] += __shfl_xor(acc[t], m, 64);
    }
    if (lane < 16) {
        float iv = 1.f / dn;
        int c = 8 * q;
        float4 b0 = *(const float4*)(b1 + c),   b4 = *(const float4*)(b1 + c + 4);
        float4 g0 = *(const float4*)(g1 + c),   g4 = *(const float4*)(g1 + c + 4);
        float4 e0 = *(const float4*)(be1 + c),  e4 = *(const float4*)(be1 + c + 4);
        float4 m0 = *(const float4*)(mu1 + c),  m4 = *(const float4*)(mu1 + c + 4);
        float4 v0 = *(const float4*)(var1 + c), v4 = *(const float4*)(var1 + c + 4);
        const float* bp = (const float*)&b0;  const float* bp4 = (const float*)&b4;
        const float* gp = (const float*)&g0;  const float* gp4 = (const float*)&g4;
        const float* ep = (const float*)&e0;  const float* ep4 = (const float*)&e4;
        const float* mp = (const float*)&m0;  const float* mp4 = (const float*)&m4;
        const float* vp = (const float*)&v0;  const float* vp4 = (const float*)&v4;
        f16x8 ov;
#pragma unroll
        for (int t = 0; t < 4; ++t) {
            float u = acc[t] * iv + bp[t];
            u = (u - mp[t]) * (gp[t] * rsqrtf(vp[t] + BNEPS)) + ep[t];
            u = (u > 0.f) ? u : (__expf(u) - 1.f);
            ov[t] = (_Float16)u;
        }
#pragma unroll
        for (int t = 0; t < 4; ++t) {
            float u = acc[4 + t] * iv + bp4[t];
            u = (u - mp4[t]) * (gp4[t] * rsqrtf(vp4[t] + BNEPS)) + ep4[t];
            u = (u > 0.f) ? u : (__expf(u) - 1.f);
            ov[4 + t] = (_Float16)u;
        }
        *(f16x8*)&hbn1h[(size_t)node * 128 + c] = ov;
    }
}

// ---------------- GEMM2 (MFMA): h2 = hbn1 @ W2^T [N,32] fp16 + s_src2/s_dst2 [N] ----------------
__global__ __launch_bounds__(256) void gemm2_kernel(
    const _Float16* __restrict__ hbn1h, const float* __restrict__ W2,
    const float* __restrict__ asrc2, const float* __restrict__ adst2,
    __half2* __restrict__ h2h, float* __restrict__ ssrc2, float* __restrict__ sdst2, int n)
{
    __shared__ _Float16 Ws[32 * 136];
    int tid = threadIdx.x, lane = tid & 63, wv = tid >> 6;
    {
        int c = tid >> 3, k0 = (tid & 7) * 16;
        const float4* src = (const float4*)(W2 + (size_t)c * 128 + k0);
        _Float16* dst = &Ws[c * 136 + k0];
#pragma unroll
        for (int i = 0; i < 4; ++i) {
            float4 v = src[i];
            dst[4 * i + 0] = (_Float16)v.x; dst[4 * i + 1] = (_Float16)v.y;
            dst[4 * i + 2] = (_Float16)v.z; dst[4 * i + 3] = (_Float16)v.w;
        }
    }
    __syncthreads();

    int rbase = blockIdx.x * 64 + wv * 16;
    int q = lane & 15, kg = lane >> 4;
    int arow = min(rbase + q, n - 1);
    f32x4 acc[2];
    acc[0] = (f32x4){0.f, 0.f, 0.f, 0.f};
    acc[1] = (f32x4){0.f, 0.f, 0.f, 0.f};
#pragma unroll
    for (int kt = 0; kt < 4; ++kt) {
        f16x8 a = *(const f16x8*)&hbn1h[(size_t)arow * 128 + kt * 32 + kg * 8];
#pragma unroll
        for (int t = 0; t < 2; ++t) {
            f16x8 b = *(const f16x8*)&Ws[(t * 16 + q) * 136 + kt * 32 + kg * 8];
            acc[t] = __builtin_amdgcn_mfma_f32_16x16x32_f16(a, b, acc[t], 0, 0, 0);
        }
    }

    float sp[4] = {0.f, 0.f, 0.f, 0.f}, sd[4] = {0.f, 0.f, 0.f, 0.f};
#pragma unroll
    for (int t = 0; t < 2; ++t) {
        float as = asrc2[t * 16 + q], ad = adst2[t * 16 + q];
#pragma unroll
        for (int i = 0; i < 4; ++i) {
            sp[i] += acc[t][i] * as;
            sd[i] += acc[t][i] * ad;
        }
    }
#pragma unroll
    for (int m = 1; m <= 8; m <<= 1) {
#pragma unroll
        for (int i = 0; i < 4; ++i) {
            sp[i] += __shfl_xor(sp[i], m, 64);
            sd[i] += __shfl_xor(sd[i], m, 64);
        }
    }
    if (q == 0) {
#pragma unroll
        for (int i = 0; i < 4; ++i) {
            int row = rbase + kg * 4 + i;
            if (row < n) { ssrc2[row] = sp[i]; sdst2[row] = sd[i]; }
        }
    }
#pragma unroll
    for (int t = 0; t < 2; ++t) {
#pragma unroll
        for (int i = 0; i < 4; ++i) {
            float v = acc[t][i];
            float vn = __shfl_xor(v, 1, 64);
            if ((q & 1) == 0) {
                int row = rbase + kg * 4 + i;
                if (row < n)
                    h2h[(size_t)row * 16 + t * 8 + (q >> 1)] = __floats2half2_rn(v, vn);
            }
        }
    }
}

// ---------------- GAT layer-2: 8-streams x 2 nodes/wave aggregate + BN2 + ELU + classifier -------
// lane: bit5 = node, bits2-4 = edge stream (8), bits0-1 = channel quad (8 ch = 16B of h2h row).
__global__ __launch_bounds__(256) void agg2_kernel(
    const __half2* __restrict__ h2h, const float* __restrict__ ssrc2, const float* __restrict__ sdst2,
    const int* __restrict__ rowptr, const int* __restrict__ col,
    const float* __restrict__ b2, const float* __restrict__ g2, const float* __restrict__ be2,
    const float* __restrict__ mu2, const float* __restrict__ var2,
    const float* __restrict__ Wc, const float* __restrict__ bc,
    float* __restrict__ out, int n)
{
    int tid = threadIdx.x;
    int lane = tid & 63;
    int node = blockIdx.x * 8 + (tid >> 6) * 2 + (lane >> 5);
    if (node >= n) return;
    int g = (lane >> 2) & 7;    // edge stream
    int cq = lane & 3;          // channel quad: ch 8cq..8cq+7
    int start = rowptr[node], end = rowptr[node + 1];
    float sd = sdst2[node];

    float acc[8] = {0.f, 0.f, 0.f, 0.f, 0.f, 0.f, 0.f, 0.f};
    float dn = 0.f;
    for (int j = start + g; j < end; j += 8) {
        int s = col[j];
        float e = ssrc2[s] + sd;
        e = (e > 0.f) ? e : NEG * e;
        float w = __expf(e);
        dn += w;
        float4 hv = *(const float4*)((const char*)(h2h + (size_t)s * 16) + 16 * cq);
        const __half2* hp = (const __half2*)&hv;
#pragma unroll
        for (int t = 0; t < 4; ++t) {
            float2 f = __half22float2(hp[t]);
            acc[2 * t]     += w * f.x;
            acc[2 * t + 1] += w * f.y;
        }
    }
    // combine 8 streams (lane bits 2,3,4)
#pragma unroll
    for (int m = 4; m <= 16; m <<= 1) {
        dn += __shfl_xor(dn, m, 64);
#pragma unroll
        for (int t = 0; t < 8; ++t) acc[t] += __shfl_xor(acc[t], m, 64);
    }
    float iv = 1.f / dn;
    int c = 8 * cq;
    float4 b0 = *(const float4*)(b2 + c),   b4 = *(const float4*)(b2 + c + 4);
    float4 g0 = *(const float4*)(g2 + c),   g4 = *(const float4*)(g2 + c + 4);
    float4 e0 = *(const float4*)(be2 + c),  e4 = *(const float4*)(be2 + c + 4);
    float4 m0 = *(const float4*)(mu2 + c),  m4 = *(const float4*)(mu2 + c + 4);
    float4 v0 = *(const float4*)(var2 + c), v4 = *(const float4*)(var2 + c + 4);
    const float* bp = (const float*)&b0;  const float* bp4 = (const float*)&b4;
    const float* gp = (const float*)&g0;  const float* gp4 = (const float*)&g4;
    const float* ep = (const float*)&e0;  const float* ep4 = (const float*)&e4;
    const float* mp = (const float*)&m0;  const float* mp4 = (const float*)&m4;
    const float* vp = (const float*)&v0;  const float* vp4 = (const float*)&v4;
    float v[8];
#pragma unroll
    for (int t = 0; t < 4; ++t) {
        float u = acc[t] * iv + bp[t];
        u = (u - mp[t]) * (gp[t] * rsqrtf(vp[t] + BNEPS)) + ep[t];
        v[t] = (u > 0.f) ? u : (__expf(u) - 1.f);
    }
#pragma unroll
    for (int t = 0; t < 4; ++t) {
        float u = acc[4 + t] * iv + bp4[t];
        u = (u - mp4[t]) * (gp4[t] * rsqrtf(vp4[t] + BNEPS)) + ep4[t];
        v[4 + t] = (u > 0.f) ? u : (__expf(u) - 1.f);
    }
    // classifier: stream-group g computes outputs o = g and g+8
#pragma unroll
    for (int rr = 0; rr < 2; ++rr) {
        int o = g + 8 * rr;
        float t = 0.f;
        if (o < 10) {
            const float* wc = Wc + o * 32 + c;
#pragma unroll
            for (int k = 0; k < 8; ++k) t += v[k] * wc[k];
        }
        t += __shfl_xor(t, 1, 64);
        t += __shfl_xor(t, 2, 64);
        if (cq == 0 && o < 10) out[(size_t)node * 10 + o] = t + bc[o];
    }
}

extern "C" void kernel_launch(void* const* d_in, const int* in_sizes, int n_in,
                              void* d_out, int out_size, void* d_ws, size_t ws_size,
                              hipStream_t stream)
{
    const float* x     = (const float*)d_in[0];
    const int*   ei    = (const int*)d_in[1];
    const float* W1    = (const float*)d_in[2];
    const float* asrc1 = (const float*)d_in[3];
    const float* adst1 = (const float*)d_in[4];
    const float* b1    = (const float*)d_in[5];
    const float* g1    = (const float*)d_in[6];
    const float* be1   = (const float*)d_in[7];
    const float* mu1   = (const float*)d_in[8];
    const float* var1  = (const float*)d_in[9];
    const float* W2    = (const float*)d_in[10];
    const float* asrc2 = (const float*)d_in[11];
    const float* adst2 = (const float*)d_in[12];
    const float* b2    = (const float*)d_in[13];
    const float* g2    = (const float*)d_in[14];
    const float* be2   = (const float*)d_in[15];
    const float* mu2   = (const float*)d_in[16];
    const float* var2  = (const float*)d_in[17];
    const float* Wc    = (const float*)d_in[18];
    const float* bc    = (const float*)d_in[19];

    int N_ = in_sizes[0] / 128;
    int E_ = in_sizes[1] / 2;
    int Etot = E_ + N_;
    const int* srcp = ei;
    const int* dstp = ei + E_;
    int chunk = (N_ + NPART - 1) / NPART;
    int pcap = Etot / NPART + 1024;

    char* ws = (char*)d_ws;
    size_t off = 0;
    auto alloc = [&](size_t bytes) -> char* {
        char* p = ws + off;
        off += (bytes + 255) & ~(size_t)255;
        return p;
    };
    __half2*   h1h   = (__half2*)alloc((size_t)N_ * 64 * 4);
    _Float16*  hbn1h = (_Float16*)alloc((size_t)N_ * 128 * 2);
    __half2*   h2h   = (__half2*)alloc((size_t)N_ * 16 * 4);
    float*     ssrc1 = (float*)alloc((size_t)N_ * 4 * 4);
    float*     sdst1 = (float*)alloc((size_t)N_ * 4 * 4);
    float*     ssrc2 = (float*)alloc((size_t)N_ * 4);
    float*     sdst2 = (float*)alloc((size_t)N_ * 4);
    int*       rowptr= (int*)alloc((size_t)(N_ + 1) * 4);
    int*       col   = (int*)alloc((size_t)Etot * 4);
    int2*      pairs = (int2*)alloc((size_t)NPART * pcap * 8);
    int*       pcur  = (int*)alloc((size_t)NPART * 4);

    hipMemsetAsync(pcur, 0, NPART * 4, stream);
    int gemm_blocks = (N_ + 63) / 64;
    int per_block = 256 * 8;
    int part_blocks = (Etot + per_block - 1) / per_block;
    gemm1_part_kernel<<<gemm_blocks + part_blocks, 256, 0, stream>>>(
        x, W1, asrc1, adst1, h1h, ssrc1, sdst1, N_, gemm_blocks,
        srcp, dstp, E_, Etot, chunk, pairs, pcap, pcur);
    csr_kernel<<<NPART, 256, 0, stream>>>(pairs, pcap, pcur, rowptr, col, N_, chunk, Etot);
    agg1_kernel<<<(N_ + 3) / 4, 256, 0, stream>>>(h1h, ssrc1, sdst1, rowptr, col,
                                                  b1, g1, be1, mu1, var1, hbn1h, N_);
    gemm2_kernel<<<(N_ + 63) / 64, 256, 0, stream>>>(hbn1h, W2, asrc2, adst2, h2h, ssrc2, sdst2, N_);
    agg2_kernel<<<(N_ + 7) / 8, 256, 0, stream>>>(h2h, ssrc2, sdst2, rowptr, col,
                                                  b2, g2, be2, mu2, var2, Wc, bc, (float*)d_out, N_);
}